// Round 4
// baseline (1056.092 us; speedup 1.0000x reference)
//
#include <hip/hip_runtime.h>

typedef __bf16 bf16;
typedef __bf16 bf16x8 __attribute__((ext_vector_type(8)));
typedef float floatx4 __attribute__((ext_vector_type(4)));

#define N_NODES 50000
#define N_EDGES 800000

// clamped activations: exp argument bounded; exact at f32 for |x|>40.
__device__ __forceinline__ float silu_f(float x) {
  float t = fminf(fmaxf(x, -40.f), 40.f);
  return x / (1.f + __expf(-t));
}
__device__ __forceinline__ float sigm_f(float x) {
  float t = fminf(fmaxf(x, -40.f), 40.f);
  return 1.f / (1.f + __expf(-t));
}

// ---------------- prep: f32 -> bf16 conversions ----------------
__global__ void prep_nf(const float* __restrict__ src, bf16* __restrict__ dst) {
  int i = (blockIdx.x * 256 + threadIdx.x) * 4;   // 6.4M elems, grid covers exactly
  float4 v = *(const float4*)(src + i);
  bf16 o[4] = {(bf16)v.x, (bf16)v.y, (bf16)v.z, (bf16)v.w};
  *(float2*)(dst + i) = *(float2*)o;
}

struct WJobs { const float* s[5]; bf16* d[5]; int n[5]; };
__global__ void prep_w(WJobs j) {
  int gid = blockIdx.x * 256 + threadIdx.x;
  int stride = gridDim.x * 256;
#pragma unroll
  for (int t = 0; t < 5; ++t)
    for (int i = gid; i < j.n[t]; i += stride) j.d[t][i] = (bf16)j.s[t][i];
}

// Stage one 64-K-slice of W[K][128] (bf16) into LDS transposed: Wlds[n][kk], stride 72.
__device__ __forceinline__ void stage_w(bf16* Wlds, const bf16* __restrict__ Wg,
                                        int kc, int Kreal, int tid) {
#pragma unroll
  for (int ii = 0; ii < 32; ++ii) {           // 64*128 / 256 threads
    int i = tid + ii * 256;
    int kk = i >> 7, n = i & 127;             // consecutive tid -> consecutive n (coalesced)
    int kg = kc * 64 + kk;
    Wlds[n * 72 + kk] = (kg < Kreal) ? Wg[kg * 128 + n] : (bf16)0.f;
  }
}

// One GEMM layer: 16 rows per wave (Arow pre-offset), 128 cols, K = NCH*64
// (zero-padded past Kreal). acc in MFMA C layout (col=nt*16+l15, row=quad*4+reg).
template <int NCH>
__device__ __forceinline__ void gemm(const bf16* __restrict__ Wg, int Kreal,
                                     const bf16* Arow, bf16* Wlds,
                                     int tid, int l15, int quad, floatx4 acc[8]) {
#pragma unroll
  for (int kc = 0; kc < NCH; ++kc) {
    __syncthreads();                          // previous Wlds readers done
    stage_w(Wlds, Wg, kc, Kreal, tid);
    __syncthreads();
#pragma unroll
    for (int ks = 0; ks < 64; ks += 32) {
      bf16x8 a = *(const bf16x8*)(Arow + kc * 64 + ks + quad * 8);
#pragma unroll
      for (int nt = 0; nt < 8; ++nt) {
        bf16x8 b = *(const bf16x8*)(Wlds + (nt * 16 + l15) * 72 + ks + quad * 8);
        acc[nt] = __builtin_amdgcn_mfma_f32_16x16x32_bf16(a, b, acc[nt], 0, 0, 0);
      }
    }
  }
}

// ---------------- edge kernel: 64 edges per block ----------------
__global__ __launch_bounds__(256, 2) void edge_kernel(
    const bf16* __restrict__ nfb, const float* __restrict__ coords, const float* __restrict__ ef,
    const bf16* __restrict__ We1, const float* __restrict__ be1,
    const bf16* __restrict__ We2, const float* __restrict__ be2,
    const bf16* __restrict__ Wc1, const float* __restrict__ bc1, const float* __restrict__ Wc,
    const float* __restrict__ Wa, const float* __restrict__ ba,
    const int* __restrict__ src, const int* __restrict__ dst,
    float* __restrict__ m_agg, float* __restrict__ agg, float* __restrict__ cnt,
    const float* ws_lim) {
  // A tile: k 0-127 h_src, 128-255 h_dst, 256 radial, 257-288 ef, 289-319 zero pad
  __shared__ __align__(16) bf16 Alds[64 * 328];
  __shared__ __align__(16) bf16 Wlds[128 * 72];
  __shared__ float cdL[64][3];
  __shared__ float cL[64];
  __shared__ int sIdx[64], dIdx[64];

  const int tid = threadIdx.x;
  const int lane = tid & 63;
  const int wv = tid >> 6;
  const int l15 = lane & 15;
  const int quad = lane >> 4;
  const int r0 = wv * 16;
  const int e0 = blockIdx.x * 64;

  // zero the pad region k 289..319 (and radial slot rewritten below)
  for (int i = tid; i < 64 * 40; i += 256) {
    int r = i / 40, k = 280 + (i - r * 40);
    Alds[r * 328 + k] = (bf16)0.f;
  }

  if (tid < 64) {
    int e = e0 + tid;
    int s = src[e], d = dst[e];
    if ((unsigned)s >= N_NODES) s = 0;
    if ((unsigned)d >= N_NODES) d = 0;
    sIdx[tid] = s; dIdx[tid] = d;
    float dx = coords[s * 3 + 0] - coords[d * 3 + 0];
    float dy = coords[s * 3 + 1] - coords[d * 3 + 1];
    float dz = coords[s * 3 + 2] - coords[d * 3 + 2];
    cdL[tid][0] = dx; cdL[tid][1] = dy; cdL[tid][2] = dz;
    Alds[tid * 328 + 256] = (bf16)(dx * dx + dy * dy + dz * dz);
  }
  __syncthreads();
  // gather h_src / h_dst from bf16 nf (16B = 8 bf16 per lane-chunk)
#pragma unroll
  for (int ii = 0; ii < 8; ++ii) {            // 64 rows * 32 chunks / 256 threads
    int i = tid + ii * 256;
    int r = i >> 5, c = i & 31;
    int node = (c < 16) ? sIdx[r] : dIdx[r];
    int k0 = (c & 15) << 3;
    *(float4*)(Alds + r * 328 + ((c < 16) ? 0 : 128) + k0) =
        *(const float4*)(nfb + (size_t)node * 128 + k0);
  }
  // edge feats f32 -> bf16 (k 257..288)
  for (int i = tid; i < 64 * 32; i += 256) {
    int r = i >> 5, j = i & 31;
    Alds[r * 328 + 257 + j] = (bf16)ef[(size_t)(e0 + r) * 32 + j];
  }

  const bf16* Arow = Alds + (r0 + l15) * 328;
  const floatx4 z4 = {0.f, 0.f, 0.f, 0.f};
  floatx4 acc[8];
#pragma unroll
  for (int nt = 0; nt < 8; ++nt) acc[nt] = z4;

  // ---- layer e1: K=289 (5 chunks of 64) ----
  gemm<5>(We1, 289, Arow, Wlds, tid, l15, quad, acc);
#pragma unroll
  for (int nt = 0; nt < 8; ++nt) {
    int col = nt * 16 + l15;
    float b = be1[col];
#pragma unroll
    for (int i = 0; i < 4; ++i)
      Alds[(r0 + quad * 4 + i) * 328 + col] = (bf16)silu_f(acc[nt][i] + b);
    acc[nt] = z4;
  }

  // ---- layer e2: K=128 ----
  gemm<2>(We2, 128, Arow, Wlds, tid, l15, quad, acc);
  float m2[8][4];
  float part[4] = {0.f, 0.f, 0.f, 0.f};
#pragma unroll
  for (int nt = 0; nt < 8; ++nt) {
    int col = nt * 16 + l15;
    float b = be2[col];
    float wa = Wa[col];
#pragma unroll
    for (int i = 0; i < 4; ++i) {
      float v = silu_f(acc[nt][i] + b);
      m2[nt][i] = v;
      part[i] += v * wa;                      // attention dot partial (this lane's 8 cols)
    }
    acc[nt] = z4;
  }
#pragma unroll
  for (int off = 1; off < 16; off <<= 1)
#pragma unroll
    for (int i = 0; i < 4; ++i) part[i] += __shfl_xor(part[i], off, 64);
  float ba_f = ba[0];
#pragma unroll
  for (int i = 0; i < 4; ++i) {
    float g = sigm_f(part[i] + ba_f);
#pragma unroll
    for (int nt = 0; nt < 8; ++nt) m2[nt][i] *= g;
  }
  // gated m -> LDS rows (A operand for coord layer)
#pragma unroll
  for (int nt = 0; nt < 8; ++nt) {
    int col = nt * 16 + l15;
#pragma unroll
    for (int i = 0; i < 4; ++i)
      Alds[(r0 + quad * 4 + i) * 328 + col] = (bf16)m2[nt][i];
  }

  // ---- coord layer: q = silu(m@Wc1+bc1), c = q.Wc ----
  gemm<2>(Wc1, 128, Arow, Wlds, tid, l15, quad, acc);
  float partc[4] = {0.f, 0.f, 0.f, 0.f};
#pragma unroll
  for (int nt = 0; nt < 8; ++nt) {
    int col = nt * 16 + l15;
    float b = bc1[col];
    float wc = Wc[col];
#pragma unroll
    for (int i = 0; i < 4; ++i) partc[i] += silu_f(acc[nt][i] + b) * wc;
  }
#pragma unroll
  for (int off = 1; off < 16; off <<= 1)
#pragma unroll
    for (int i = 0; i < 4; ++i) partc[i] += __shfl_xor(partc[i], off, 64);
  if (l15 == 0)
#pragma unroll
    for (int i = 0; i < 4; ++i) cL[r0 + quad * 4 + i] = partc[i];

  // ---- scatter gated m into m_agg (f32 atomics, bounds-guarded) ----
#pragma unroll
  for (int i = 0; i < 4; ++i) {
    int row = r0 + quad * 4 + i;
    int d = dIdx[row];
#pragma unroll
    for (int nt = 0; nt < 8; ++nt) {
      float* p = &m_agg[(size_t)d * 128 + nt * 16 + l15];
      if (p < ws_lim) atomicAdd(p, m2[nt][i]);
    }
  }
  __syncthreads();
  // ---- scatter coord update ----
  if (tid < 64) {
    int d = dIdx[tid];
    float c = cL[tid];
    if (&agg[d * 3 + 2] < ws_lim) {
      atomicAdd(&agg[d * 3 + 0], cdL[tid][0] * c);
      atomicAdd(&agg[d * 3 + 1], cdL[tid][1] * c);
      atomicAdd(&agg[d * 3 + 2], cdL[tid][2] * c);
    }
    if (&cnt[d] < ws_lim) atomicAdd(&cnt[d], 1.0f);
  }
}

// ---------------- node kernel: 64 nodes per block ----------------
__global__ __launch_bounds__(256, 2) void node_kernel(
    const bf16* __restrict__ nfb, const float* __restrict__ nf,
    const float* __restrict__ coords,
    const bf16* __restrict__ Wn1, const float* __restrict__ bn1,
    const bf16* __restrict__ Wn2, const float* __restrict__ bn2,
    const float* __restrict__ m_agg, const float* __restrict__ agg,
    const float* __restrict__ cnt,
    float* __restrict__ h_out, float* __restrict__ c_out,
    const float* ws_lim) {
  __shared__ __align__(16) bf16 Alds[64 * 264];  // k 0-127 h, 128-255 m_agg then h1
  __shared__ __align__(16) bf16 Wlds[128 * 72];

  const int tid = threadIdx.x;
  const int lane = tid & 63;
  const int wv = tid >> 6;
  const int l15 = lane & 15;
  const int quad = lane >> 4;
  const int r0 = wv * 16;
  const int n0 = blockIdx.x * 64;

  // coordinate output (independent of LDS)
  if (tid < 64) {
    int n = n0 + tid;
    if (n < N_NODES) {
      float cn = (&cnt[n] < ws_lim) ? cnt[n] : 1.f;
      float inv = 1.f / fmaxf(cn, 1.f);
#pragma unroll
      for (int j = 0; j < 3; ++j) {
        float a = (&agg[n * 3 + j] < ws_lim) ? agg[n * 3 + j] : 0.f;
        c_out[n * 3 + j] = coords[n * 3 + j] + a * inv;
      }
    }
  }
  // stage h (bf16)
#pragma unroll
  for (int ii = 0; ii < 4; ++ii) {            // 64 rows * 16 chunks / 256 threads
    int i = tid + ii * 256;
    int r = i >> 4, c = i & 15;
    int n = n0 + r;
    float4 v = {0.f, 0.f, 0.f, 0.f};          // 8 bf16
    if (n < N_NODES) v = *(const float4*)(nfb + (size_t)n * 128 + c * 8);
    *(float4*)(Alds + r * 264 + c * 8) = v;
  }
  // stage m_agg (f32 -> bf16)
#pragma unroll
  for (int ii = 0; ii < 32; ++ii) {           // 64 rows * 128 / 256 threads
    int i = tid + ii * 256;
    int r = i >> 7, k = i & 127;
    int n = n0 + r;
    float v = 0.f;
    if (n < N_NODES) {
      const float* p = &m_agg[(size_t)n * 128 + k];
      v = (p < ws_lim) ? *p : 0.f;
    }
    Alds[r * 264 + 128 + k] = (bf16)v;
  }

  const bf16* Arow = Alds + (r0 + l15) * 264;
  const floatx4 z4 = {0.f, 0.f, 0.f, 0.f};
  floatx4 acc[8];
#pragma unroll
  for (int nt = 0; nt < 8; ++nt) acc[nt] = z4;

  // ---- layer n1: K=256 ----
  gemm<4>(Wn1, 256, Arow, Wlds, tid, l15, quad, acc);
#pragma unroll
  for (int nt = 0; nt < 8; ++nt) {
    int col = nt * 16 + l15;
    float b = bn1[col];
#pragma unroll
    for (int i = 0; i < 4; ++i)
      Alds[(r0 + quad * 4 + i) * 264 + 128 + col] = (bf16)silu_f(acc[nt][i] + b);
    acc[nt] = z4;
  }

  // ---- layer n2: K=128, residual from f32 nf ----
  gemm<2>(Wn2, 128, Arow + 128, Wlds, tid, l15, quad, acc);
#pragma unroll
  for (int nt = 0; nt < 8; ++nt) {
    int col = nt * 16 + l15;
    float b = bn2[col];
#pragma unroll
    for (int i = 0; i < 4; ++i) {
      int row = r0 + quad * 4 + i;
      int n = n0 + row;
      if (n < N_NODES)
        h_out[(size_t)n * 128 + col] = nf[(size_t)n * 128 + col] + acc[nt][i] + b;
    }
  }
}

extern "C" void kernel_launch(void* const* d_in, const int* in_sizes, int n_in,
                              void* d_out, int out_size, void* d_ws, size_t ws_size,
                              hipStream_t stream) {
  const float* nf     = (const float*)d_in[0];
  const float* coords = (const float*)d_in[1];
  const float* ef     = (const float*)d_in[2];
  const float* We1    = (const float*)d_in[3];
  const float* be1    = (const float*)d_in[4];
  const float* We2    = (const float*)d_in[5];
  const float* be2    = (const float*)d_in[6];
  const float* Wn1    = (const float*)d_in[7];
  const float* bn1    = (const float*)d_in[8];
  const float* Wn2    = (const float*)d_in[9];
  const float* bn2    = (const float*)d_in[10];
  const float* Wc1    = (const float*)d_in[11];
  const float* bc1    = (const float*)d_in[12];
  const float* Wc     = (const float*)d_in[13];
  const float* Wa     = (const float*)d_in[14];
  const float* ba     = (const float*)d_in[15];
  const int*   src    = (const int*)d_in[16];
  const int*   dst    = (const int*)d_in[17];

  // ws layout (floats first, zeroed): agg[3N], cnt[N], m_agg[N*128]; then bf16 region
  float* agg   = (float*)d_ws;
  float* cnt   = agg + (size_t)3 * N_NODES;
  float* m_agg = cnt + N_NODES;
  bf16* nfb    = (bf16*)(m_agg + (size_t)N_NODES * 128);
  bf16* We1b   = nfb + (size_t)N_NODES * 128;
  bf16* We2b   = We1b + 289 * 128;
  bf16* Wn1b   = We2b + 128 * 128;
  bf16* Wn2b   = Wn1b + 256 * 128;
  bf16* Wc1b   = Wn2b + 128 * 128;
  const float* ws_lim = (const float*)((const char*)d_ws + ws_size);
  size_t zb = ((size_t)3 * N_NODES + N_NODES + (size_t)N_NODES * 128) * sizeof(float);
  if (zb > ws_size) zb = ws_size;
  hipMemsetAsync(d_ws, 0, zb, stream);

  prep_nf<<<(N_NODES * 128) / (256 * 4), 256, 0, stream>>>(nf, nfb);
  WJobs wj;
  wj.s[0] = We1; wj.d[0] = We1b; wj.n[0] = 289 * 128;
  wj.s[1] = We2; wj.d[1] = We2b; wj.n[1] = 128 * 128;
  wj.s[2] = Wn1; wj.d[2] = Wn1b; wj.n[2] = 256 * 128;
  wj.s[3] = Wn2; wj.d[3] = Wn2b; wj.n[3] = 128 * 128;
  wj.s[4] = Wc1; wj.d[4] = Wc1b; wj.n[4] = 128 * 128;
  prep_w<<<128, 256, 0, stream>>>(wj);

  float* h_out = (float*)d_out;
  float* c_out = h_out + (size_t)N_NODES * 128;

  edge_kernel<<<N_EDGES / 64, 256, 0, stream>>>(nfb, coords, ef, We1b, be1, We2b, be2,
                                                Wc1b, bc1, Wc, Wa, ba, src, dst,
                                                m_agg, agg, cnt, ws_lim);
  node_kernel<<<(N_NODES + 63) / 64, 256, 0, stream>>>(nfb, nf, coords, Wn1b, bn1, Wn2b, bn2,
                                                       m_agg, agg, cnt, h_out, c_out, ws_lim);
}

// Round 5
// 748.876 us; speedup vs baseline: 1.4102x; 1.4102x over previous
//
#include <hip/hip_runtime.h>

typedef __bf16 bf16;
typedef __bf16 bf16x8 __attribute__((ext_vector_type(8)));
typedef float floatx4 __attribute__((ext_vector_type(4)));

#define N_NODES 50000
#define N_EDGES 800000

__device__ __forceinline__ float silu_f(float x) {
  float t = fminf(fmaxf(x, -40.f), 40.f);
  return x / (1.f + __expf(-t));
}
__device__ __forceinline__ float sigm_f(float x) {
  float t = fminf(fmaxf(x, -40.f), 40.f);
  return 1.f / (1.f + __expf(-t));
}

// ---------------- prep: f32 -> bf16 ----------------
__global__ void prep_nf(const float* __restrict__ src, bf16* __restrict__ dst) {
  int i = (blockIdx.x * 256 + threadIdx.x) * 4;
  float4 v = *(const float4*)(src + i);
  bf16 o[4] = {(bf16)v.x, (bf16)v.y, (bf16)v.z, (bf16)v.w};
  *(float2*)(dst + i) = *(float2*)o;
}

// transpose+convert weights: Wt[n*Kp + k] = W[k*128 + n], zero-padded to Kp
struct TW { const float* s[5]; int K[5]; int Kp[5]; int off[5]; };
__global__ void prep_tw(TW j, bf16* __restrict__ out) {
  int g = blockIdx.x * 256 + threadIdx.x;
#pragma unroll
  for (int t = 0; t < 5; ++t) {
    int sz = 128 * j.Kp[t];
    if (g < sz) {
      int n = g / j.Kp[t], k = g - n * j.Kp[t];
      out[j.off[t] + g] = (k < j.K[t]) ? (bf16)j.s[t][(size_t)k * 128 + n] : (bf16)0.f;
      return;
    }
    g -= sz;
  }
}

// stage one 64-wide K-chunk of Wt into LDS [128][64] with XOR chunk swizzle.
// write: 4 x b128 per thread, coalesced 16B global reads, bank-floor LDS writes.
__device__ __forceinline__ void stage_w(bf16* __restrict__ Wl, const bf16* __restrict__ Wt,
                                        int Kp, int kc, int tid) {
#pragma unroll
  for (int jj = 0; jj < 4; ++jj) {
    int g = tid + jj * 256;
    int n = g >> 3, c = g & 7;
    *(float4*)(Wl + n * 64 + ((c ^ (n & 7)) << 3)) =
        *(const float4*)(Wt + (size_t)n * Kp + kc * 64 + c * 8);
  }
}

// one 32-wide k-step: 8 col-tiles, B loaded once, 2 row-subtiles share it.
__device__ __forceinline__ void mfma_step(const bf16* __restrict__ Wl, int l15, int quad,
                                          bf16x8 a0, bf16x8 a1, int ks, floatx4 acc[2][8]) {
#pragma unroll
  for (int nt = 0; nt < 8; ++nt) {
    int n = nt * 16 + l15;
    bf16x8 b = *(const bf16x8*)(Wl + n * 64 + ((((ks >> 3) + quad) ^ (n & 7)) << 3));
    acc[0][nt] = __builtin_amdgcn_mfma_f32_16x16x32_bf16(a0, b, acc[0][nt], 0, 0, 0);
    acc[1][nt] = __builtin_amdgcn_mfma_f32_16x16x32_bf16(a1, b, acc[1][nt], 0, 0, 0);
  }
}

#define SX 136  // X stride (dword stride 68 === 4 mod 32 -> bank-group parallel floor)

// ---------------- edge kernel: 128 edges/block, 4 waves x 32 rows ----------------
__global__ __launch_bounds__(256, 3) void edge_kernel(
    const bf16* __restrict__ nfb, const float* __restrict__ coords,
    const float* __restrict__ ef,
    const bf16* __restrict__ We1t, const float* __restrict__ be1,
    const bf16* __restrict__ We2t, const float* __restrict__ be2,
    const bf16* __restrict__ Wc1t, const float* __restrict__ bc1,
    const float* __restrict__ Wc, const float* __restrict__ Wa,
    const float* __restrict__ ba,
    const int* __restrict__ src, const int* __restrict__ dst,
    float* __restrict__ m_agg, float* __restrict__ agg, float* __restrict__ cnt) {
  __shared__ __align__(16) bf16 X[128 * SX];   // h1, then gated m (rows wave-private)
  __shared__ __align__(16) bf16 Wl[128 * 64];  // swizzled W chunk
  __shared__ int sIdx[128], dIdx[128];
  __shared__ float cdL[128][3];
  __shared__ float radL[128];

  const int tid = threadIdx.x;
  const int lane = tid & 63;
  const int wv = tid >> 6;
  const int l15 = lane & 15;
  const int quad = lane >> 4;
  const int r0 = wv * 32;
  const int e0 = blockIdx.x * 128;

  if (tid < 128) {
    int e = e0 + tid;
    int s = src[e], d = dst[e];
    if ((unsigned)s >= N_NODES) s = 0;
    if ((unsigned)d >= N_NODES) d = 0;
    sIdx[tid] = s; dIdx[tid] = d;
    float dx = coords[s * 3 + 0] - coords[d * 3 + 0];
    float dy = coords[s * 3 + 1] - coords[d * 3 + 1];
    float dz = coords[s * 3 + 2] - coords[d * 3 + 2];
    cdL[tid][0] = dx; cdL[tid][1] = dy; cdL[tid][2] = dz;
    radL[tid] = dx * dx + dy * dy + dz * dz;
  }
  __syncthreads();

  const floatx4 z4 = {0.f, 0.f, 0.f, 0.f};
  floatx4 acc[2][8];
#pragma unroll
  for (int t = 0; t < 2; ++t)
#pragma unroll
    for (int nt = 0; nt < 8; ++nt) acc[t][nt] = z4;

  // ---- layer e1: K=320 (289 real), kc 0..4; A-frags gathered from global ----
  for (int kc = 0; kc < 5; ++kc) {
    __syncthreads();
    bf16x8 a[2][2];
#pragma unroll
    for (int t = 0; t < 2; ++t) {
      int row = r0 + t * 16 + l15;
      if (kc < 4) {
        int node = (kc < 2) ? sIdx[row] : dIdx[row];
        const bf16* p = nfb + (size_t)node * 128 + (kc & 1) * 64 + quad * 8;
        a[t][0] = *(const bf16x8*)(p);
        a[t][1] = *(const bf16x8*)(p + 32);
      } else {
#pragma unroll
        for (int s = 0; s < 2; ++s)
#pragma unroll
          for (int jj = 0; jj < 8; ++jj) {
            int k = s * 32 + quad * 8 + jj;   // m_in col 256+k
            float v = 0.f;
            if (k == 0) v = radL[row];
            else if (k <= 32) v = ef[(size_t)(e0 + row) * 32 + (k - 1)];
            a[t][s][jj] = (bf16)v;
          }
      }
    }
    stage_w(Wl, We1t, 320, kc, tid);
    __syncthreads();
    mfma_step(Wl, l15, quad, a[0][0], a[1][0], 0, acc);
    mfma_step(Wl, l15, quad, a[0][1], a[1][1], 32, acc);
  }
  // epilogue e1: h1 = silu(acc+b) -> X
#pragma unroll
  for (int t = 0; t < 2; ++t)
#pragma unroll
    for (int nt = 0; nt < 8; ++nt) {
      int col = nt * 16 + l15;
      float b = be1[col];
#pragma unroll
      for (int i = 0; i < 4; ++i) {
        X[(r0 + t * 16 + quad * 4 + i) * SX + col] = (bf16)silu_f(acc[t][nt][i] + b);
        acc[t][nt][i] = 0.f;
      }
    }

  // ---- layer e2: K=128, A from X ----
  for (int kc = 0; kc < 2; ++kc) {
    __syncthreads();
    bf16x8 a[2][2];
#pragma unroll
    for (int t = 0; t < 2; ++t) {
      const bf16* p = X + (r0 + t * 16 + l15) * SX + kc * 64 + quad * 8;
      a[t][0] = *(const bf16x8*)(p);
      a[t][1] = *(const bf16x8*)(p + 32);
    }
    stage_w(Wl, We2t, 128, kc, tid);
    __syncthreads();
    mfma_step(Wl, l15, quad, a[0][0], a[1][0], 0, acc);
    mfma_step(Wl, l15, quad, a[0][1], a[1][1], 32, acc);
  }
  // epilogue e2: silu, attention gate, write gated m to X, scatter m_agg
  float part[2][4] = {{0.f, 0.f, 0.f, 0.f}, {0.f, 0.f, 0.f, 0.f}};
#pragma unroll
  for (int t = 0; t < 2; ++t)
#pragma unroll
    for (int nt = 0; nt < 8; ++nt) {
      int col = nt * 16 + l15;
      float b = be2[col], wa = Wa[col];
#pragma unroll
      for (int i = 0; i < 4; ++i) {
        float v = silu_f(acc[t][nt][i] + b);
        acc[t][nt][i] = v;
        part[t][i] += v * wa;
      }
    }
#pragma unroll
  for (int off = 1; off < 16; off <<= 1)
#pragma unroll
    for (int t = 0; t < 2; ++t)
#pragma unroll
      for (int i = 0; i < 4; ++i) part[t][i] += __shfl_xor(part[t][i], off, 64);
  float ba_f = ba[0];
#pragma unroll
  for (int t = 0; t < 2; ++t)
#pragma unroll
    for (int i = 0; i < 4; ++i) {
      float g = sigm_f(part[t][i] + ba_f);
#pragma unroll
      for (int nt = 0; nt < 8; ++nt) acc[t][nt][i] *= g;
    }
#pragma unroll
  for (int t = 0; t < 2; ++t)
#pragma unroll
    for (int nt = 0; nt < 8; ++nt) {
      int col = nt * 16 + l15;
#pragma unroll
      for (int i = 0; i < 4; ++i)
        X[(r0 + t * 16 + quad * 4 + i) * SX + col] = (bf16)acc[t][nt][i];
    }
  // scatter gated m (f32 atomics) — issued early so they overlap layer 3
#pragma unroll
  for (int t = 0; t < 2; ++t)
#pragma unroll
    for (int i = 0; i < 4; ++i) {
      int row = r0 + t * 16 + quad * 4 + i;
      size_t base = (size_t)dIdx[row] * 128;
#pragma unroll
      for (int nt = 0; nt < 8; ++nt)
        atomicAdd(&m_agg[base + nt * 16 + l15], acc[t][nt][i]);
      acc[t][0][i] = acc[t][0][i];  // keep
    }
#pragma unroll
  for (int t = 0; t < 2; ++t)
#pragma unroll
    for (int nt = 0; nt < 8; ++nt) acc[t][nt] = z4;

  // ---- coord layer: K=128, A = gated m from X ----
  for (int kc = 0; kc < 2; ++kc) {
    __syncthreads();
    bf16x8 a[2][2];
#pragma unroll
    for (int t = 0; t < 2; ++t) {
      const bf16* p = X + (r0 + t * 16 + l15) * SX + kc * 64 + quad * 8;
      a[t][0] = *(const bf16x8*)(p);
      a[t][1] = *(const bf16x8*)(p + 32);
    }
    stage_w(Wl, Wc1t, 128, kc, tid);
    __syncthreads();
    mfma_step(Wl, l15, quad, a[0][0], a[1][0], 0, acc);
    mfma_step(Wl, l15, quad, a[0][1], a[1][1], 32, acc);
  }
  float partc[2][4] = {{0.f, 0.f, 0.f, 0.f}, {0.f, 0.f, 0.f, 0.f}};
#pragma unroll
  for (int t = 0; t < 2; ++t)
#pragma unroll
    for (int nt = 0; nt < 8; ++nt) {
      int col = nt * 16 + l15;
      float b = bc1[col], wc = Wc[col];
#pragma unroll
      for (int i = 0; i < 4; ++i) partc[t][i] += silu_f(acc[t][nt][i] + b) * wc;
    }
#pragma unroll
  for (int off = 1; off < 16; off <<= 1)
#pragma unroll
    for (int t = 0; t < 2; ++t)
#pragma unroll
      for (int i = 0; i < 4; ++i) partc[t][i] += __shfl_xor(partc[t][i], off, 64);
  if (l15 == 0) {
#pragma unroll
    for (int t = 0; t < 2; ++t)
#pragma unroll
      for (int i = 0; i < 4; ++i) {
        int row = r0 + t * 16 + quad * 4 + i;
        int d = dIdx[row];
        float c = partc[t][i];
        atomicAdd(&agg[d * 3 + 0], cdL[row][0] * c);
        atomicAdd(&agg[d * 3 + 1], cdL[row][1] * c);
        atomicAdd(&agg[d * 3 + 2], cdL[row][2] * c);
        atomicAdd(&cnt[d], 1.0f);
      }
  }
}

// ---------------- node kernel: 128 nodes/block ----------------
__global__ __launch_bounds__(256, 3) void node_kernel(
    const bf16* __restrict__ nfb, const float* __restrict__ nf,
    const float* __restrict__ coords,
    const bf16* __restrict__ Wn1t, const float* __restrict__ bn1,
    const bf16* __restrict__ Wn2t, const float* __restrict__ bn2,
    const float* __restrict__ m_agg, const float* __restrict__ agg,
    const float* __restrict__ cnt,
    float* __restrict__ h_out, float* __restrict__ c_out) {
  __shared__ __align__(16) bf16 X[128 * SX];
  __shared__ __align__(16) bf16 Wl[128 * 64];

  const int tid = threadIdx.x;
  const int lane = tid & 63;
  const int wv = tid >> 6;
  const int l15 = lane & 15;
  const int quad = lane >> 4;
  const int r0 = wv * 32;
  const int n0 = blockIdx.x * 128;

  if (tid < 128) {
    int n = n0 + tid;
    if (n < N_NODES) {
      float inv = 1.f / fmaxf(cnt[n], 1.f);
#pragma unroll
      for (int j = 0; j < 3; ++j)
        c_out[n * 3 + j] = coords[n * 3 + j] + agg[n * 3 + j] * inv;
    }
  }

  const floatx4 z4 = {0.f, 0.f, 0.f, 0.f};
  floatx4 acc[2][8];
#pragma unroll
  for (int t = 0; t < 2; ++t)
#pragma unroll
    for (int nt = 0; nt < 8; ++nt) acc[t][nt] = z4;

  // ---- n1: K=256 (cols 0-127 h from nfb, 128-255 m_agg f32->bf16) ----
  for (int kc = 0; kc < 4; ++kc) {
    __syncthreads();
    bf16x8 a[2][2];
#pragma unroll
    for (int t = 0; t < 2; ++t) {
      int n = n0 + r0 + t * 16 + l15;
      bool ok = n < N_NODES;
#pragma unroll
      for (int s = 0; s < 2; ++s) {
        if (kc < 2) {
          bf16x8 f = {};
          if (ok) f = *(const bf16x8*)(nfb + (size_t)n * 128 + kc * 64 + s * 32 + quad * 8);
          a[t][s] = f;
        } else {
          bf16x8 f;
          if (ok) {
            const float* p = m_agg + (size_t)n * 128 + (kc - 2) * 64 + s * 32 + quad * 8;
            float4 u0 = *(const float4*)(p);
            float4 u1 = *(const float4*)(p + 4);
            f[0] = (bf16)u0.x; f[1] = (bf16)u0.y; f[2] = (bf16)u0.z; f[3] = (bf16)u0.w;
            f[4] = (bf16)u1.x; f[5] = (bf16)u1.y; f[6] = (bf16)u1.z; f[7] = (bf16)u1.w;
          } else {
            bf16x8 zz = {};
            f = zz;
          }
          a[t][s] = f;
        }
      }
    }
    stage_w(Wl, Wn1t, 256, kc, tid);
    __syncthreads();
    mfma_step(Wl, l15, quad, a[0][0], a[1][0], 0, acc);
    mfma_step(Wl, l15, quad, a[0][1], a[1][1], 32, acc);
  }
#pragma unroll
  for (int t = 0; t < 2; ++t)
#pragma unroll
    for (int nt = 0; nt < 8; ++nt) {
      int col = nt * 16 + l15;
      float b = bn1[col];
#pragma unroll
      for (int i = 0; i < 4; ++i) {
        X[(r0 + t * 16 + quad * 4 + i) * SX + col] = (bf16)silu_f(acc[t][nt][i] + b);
        acc[t][nt][i] = 0.f;
      }
    }

  // ---- n2: K=128, A = h1 from X; residual from f32 nf ----
  for (int kc = 0; kc < 2; ++kc) {
    __syncthreads();
    bf16x8 a[2][2];
#pragma unroll
    for (int t = 0; t < 2; ++t) {
      const bf16* p = X + (r0 + t * 16 + l15) * SX + kc * 64 + quad * 8;
      a[t][0] = *(const bf16x8*)(p);
      a[t][1] = *(const bf16x8*)(p + 32);
    }
    stage_w(Wl, Wn2t, 128, kc, tid);
    __syncthreads();
    mfma_step(Wl, l15, quad, a[0][0], a[1][0], 0, acc);
    mfma_step(Wl, l15, quad, a[0][1], a[1][1], 32, acc);
  }
#pragma unroll
  for (int t = 0; t < 2; ++t)
#pragma unroll
    for (int nt = 0; nt < 8; ++nt) {
      int col = nt * 16 + l15;
      float b = bn2[col];
#pragma unroll
      for (int i = 0; i < 4; ++i) {
        int n = n0 + r0 + t * 16 + quad * 4 + i;
        if (n < N_NODES)
          h_out[(size_t)n * 128 + col] = nf[(size_t)n * 128 + col] + acc[t][nt][i] + b;
      }
    }
}

extern "C" void kernel_launch(void* const* d_in, const int* in_sizes, int n_in,
                              void* d_out, int out_size, void* d_ws, size_t ws_size,
                              hipStream_t stream) {
  const float* nf     = (const float*)d_in[0];
  const float* coords = (const float*)d_in[1];
  const float* ef     = (const float*)d_in[2];
  const float* We1    = (const float*)d_in[3];
  const float* be1    = (const float*)d_in[4];
  const float* We2    = (const float*)d_in[5];
  const float* be2    = (const float*)d_in[6];
  const float* Wn1    = (const float*)d_in[7];
  const float* bn1    = (const float*)d_in[8];
  const float* Wn2    = (const float*)d_in[9];
  const float* bn2    = (const float*)d_in[10];
  const float* Wc1    = (const float*)d_in[11];
  const float* bc1    = (const float*)d_in[12];
  const float* Wc     = (const float*)d_in[13];
  const float* Wa     = (const float*)d_in[14];
  const float* ba     = (const float*)d_in[15];
  const int*   src    = (const int*)d_in[16];
  const int*   dst    = (const int*)d_in[17];

  float* agg   = (float*)d_ws;                      // 3N
  float* cnt   = agg + (size_t)3 * N_NODES;         // N
  float* m_agg = cnt + N_NODES;                     // N*128
  bf16* nfb    = (bf16*)(m_agg + (size_t)N_NODES * 128);
  bf16* Wt     = nfb + (size_t)N_NODES * 128;       // 122880 bf16
  const int offE1 = 0;
  const int offE2 = 128 * 320;
  const int offC1 = offE2 + 128 * 128;
  const int offN1 = offC1 + 128 * 128;
  const int offN2 = offN1 + 128 * 256;

  size_t zb = ((size_t)3 * N_NODES + N_NODES + (size_t)N_NODES * 128) * sizeof(float);
  hipMemsetAsync(d_ws, 0, zb, stream);

  prep_nf<<<(N_NODES * 128) / (256 * 4), 256, 0, stream>>>(nf, nfb);
  TW tw;
  tw.s[0] = We1; tw.K[0] = 289; tw.Kp[0] = 320; tw.off[0] = offE1;
  tw.s[1] = We2; tw.K[1] = 128; tw.Kp[1] = 128; tw.off[1] = offE2;
  tw.s[2] = Wc1; tw.K[2] = 128; tw.Kp[2] = 128; tw.off[2] = offC1;
  tw.s[3] = Wn1; tw.K[3] = 256; tw.Kp[3] = 256; tw.off[3] = offN1;
  tw.s[4] = Wn2; tw.K[4] = 128; tw.Kp[4] = 128; tw.off[4] = offN2;
  prep_tw<<<480, 256, 0, stream>>>(tw, Wt);

  float* h_out = (float*)d_out;
  float* c_out = h_out + (size_t)N_NODES * 128;

  edge_kernel<<<N_EDGES / 128, 256, 0, stream>>>(
      nfb, coords, ef, Wt + offE1, be1, Wt + offE2, be2, Wt + offC1, bc1,
      Wc, Wa, ba, src, dst, m_agg, agg, cnt);
  node_kernel<<<(N_NODES + 127) / 128, 256, 0, stream>>>(
      nfb, nf, coords, Wt + offN1, bn1, Wt + offN2, bn2,
      m_agg, agg, cnt, h_out, c_out);
}